// Round 2
// baseline (161.632 us; speedup 1.0000x reference)
//
#include <hip/hip_runtime.h>
#include <hip/hip_bf16.h>

// NLL of bivariate Gaussian, log-domain formulation.
// nll = z/(2(1-rho^2)) + log(2pi) + log_sx + log_sy + 0.5*log(1-rho^2)
// Clip: -log(max(pdf, 1e-10)) == fminf(nll, -log(1e-10)).
//
// R1: coalesced global->LDS staging (unit-stride float4 across lanes), then
// AoS reads from LDS. R0's per-lane-contiguous loads (stride 80B) generated
// ~5x the L1 line requests and capped us at 2.7 TB/s.

#define THREADS 256
#define PPT 4                // points per thread
#define TILE (THREADS * PPT) // 1024 points per block

__device__ __forceinline__ float point_nll(float mux, float muy, float lsx,
                                           float lsy, float w, float y1, float y2) {
    const float LOG_2PI = 1.8378770664093453f;
    const float CLIP    = 23.025850929940457f; // -log(1e-10)
    float isx  = __expf(-lsx);
    float isy  = __expf(-lsy);
    float nx   = (y1 - mux) * isx;
    float ny   = (y2 - muy) * isy;
    float corr = tanhf(w);
    float omr  = fmaf(-corr, corr, 1.0f);          // 1 - rho^2
    float z    = fmaf(nx, nx, ny * ny) - 2.0f * corr * nx * ny;
    float nll  = z / (2.0f * omr) + LOG_2PI + lsx + lsy + 0.5f * __logf(omr);
    return fminf(nll, CLIP);                        // fminf(NaN,CLIP)=CLIP too
}

__global__ __launch_bounds__(THREADS) void nll_partial_kernel(
    const float* __restrict__ y, const float* __restrict__ o,
    float* __restrict__ partial, int N) {
    __shared__ float4 lds_o[5 * THREADS]; // 20 KB: o tile, linear float4 layout
    __shared__ float4 lds_y[3 * THREADS]; // 12 KB: y tile

    const int tid = threadIdx.x;
    const long long base_pt = (long long)blockIdx.x * TILE;
    float acc = 0.0f;

    if (base_pt + TILE <= (long long)N) {
        // Fully coalesced staging: lane-unit-stride float4 loads.
        const float4* o4 = (const float4*)o + base_pt * 5 / 4; // tile*1280
        const float4* y4 = (const float4*)y + base_pt * 3 / 4; // tile*768
#pragma unroll
        for (int k = 0; k < 5; ++k) lds_o[k * THREADS + tid] = o4[k * THREADS + tid];
#pragma unroll
        for (int k = 0; k < 3; ++k) lds_y[k * THREADS + tid] = y4[k * THREADS + tid];
        __syncthreads();

        // AoS reads from LDS: 20 floats (5x b128) + 12 floats (3x b128),
        // both 16B-aligned (tid*80 B, tid*48 B).
        const float* fo = (const float*)lds_o + tid * (PPT * 5);
        const float* fy = (const float*)lds_y + tid * (PPT * 3);
#pragma unroll
        for (int j = 0; j < PPT; ++j) {
            acc += point_nll(fo[5 * j + 0], fo[5 * j + 1], fo[5 * j + 2],
                             fo[5 * j + 3], fo[5 * j + 4],
                             fy[3 * j + 1], fy[3 * j + 2]);
        }
    } else {
        // Tail tile (not hit for N = 4,194,304): guarded scalar path.
        long long i0 = base_pt + (long long)tid * PPT;
        for (int j = 0; j < PPT; ++j) {
            long long i = i0 + j;
            if (i < (long long)N)
                acc += point_nll(o[i * 5 + 0], o[i * 5 + 1], o[i * 5 + 2],
                                 o[i * 5 + 3], o[i * 5 + 4],
                                 y[i * 3 + 1], y[i * 3 + 2]);
        }
    }

    // wave-64 reduce, then cross-wave via LDS
#pragma unroll
    for (int off = 32; off > 0; off >>= 1) acc += __shfl_down(acc, off, 64);
    __shared__ float ws[THREADS / 64];
    if ((tid & 63) == 0) ws[tid >> 6] = acc;
    __syncthreads();
    if (tid == 0) {
        float s = 0.0f;
#pragma unroll
        for (int i = 0; i < THREADS / 64; ++i) s += ws[i];
        partial[blockIdx.x] = s;
    }
}

__global__ __launch_bounds__(THREADS) void nll_final_kernel(
    const float* __restrict__ partial, int nparts, float* __restrict__ out,
    float inv_p) {
    float acc = 0.0f;
    for (int i = threadIdx.x; i < nparts; i += THREADS) acc += partial[i];
#pragma unroll
    for (int off = 32; off > 0; off >>= 1) acc += __shfl_down(acc, off, 64);
    __shared__ float ws[THREADS / 64];
    if ((threadIdx.x & 63) == 0) ws[threadIdx.x >> 6] = acc;
    __syncthreads();
    if (threadIdx.x == 0) {
        float s = 0.0f;
#pragma unroll
        for (int i = 0; i < THREADS / 64; ++i) s += ws[i];
        out[0] = s * inv_p;
    }
}

extern "C" void kernel_launch(void* const* d_in, const int* in_sizes, int n_in,
                              void* d_out, int out_size, void* d_ws, size_t ws_size,
                              hipStream_t stream) {
    const float* y = (const float*)d_in[0]; // (B,T,P,3)
    const float* o = (const float*)d_in[1]; // (B,T,P,5)
    int N = in_sizes[1] / 5;                // B*T*P points
    int blocks = (N + TILE - 1) / TILE;     // 4096 for the reference shape

    float* partial = (float*)d_ws;
    nll_partial_kernel<<<blocks, THREADS, 0, stream>>>(y, o, partial, N);
    // P = 512 (pdf.shape[2] in the reference); 1/512 is exact in fp32.
    nll_final_kernel<<<1, THREADS, 0, stream>>>(partial, blocks, (float*)d_out,
                                                1.0f / 512.0f);
}